// Round 6
// baseline (28408.670 us; speedup 1.0000x reference)
//
#include <hip/hip_runtime.h>
#include <cstdint>
#include <cmath>

typedef unsigned int u32;
typedef unsigned long long u64;

#define N_ANCH 147456   // 128*128*9
#define SORT_N 262144   // 2^18 >= N_ANCH

// ==================== direct conv 3x3 + relu, f64 accumulate ====================
__global__ __launch_bounds__(128)
void k_conv64(const float* __restrict__ feat, const float* __restrict__ cw,
              const float* __restrict__ bias, float* __restrict__ rpn) {
    int x = threadIdx.x;          // 0..127
    int y = blockIdx.x;           // 0..127
    int co = blockIdx.y;          // 0..511
    double acc = 0.0;
    const float* wco = cw + (size_t)co * 4608;
    for (int ci = 0; ci < 512; ++ci) {
        const float* fb = feat + (size_t)ci * 16384;
        const float* wb = wco + ci * 9;
#pragma unroll
        for (int ky = 0; ky < 3; ++ky) {
            int gy = y + ky - 1;
            if (gy < 0 || gy >= 128) continue;
#pragma unroll
            for (int kx = 0; kx < 3; ++kx) {
                int gx = x + kx - 1;
                if (gx < 0 || gx >= 128) continue;
                acc = fma((double)wb[ky * 3 + kx], (double)fb[gy * 128 + gx], acc);
            }
        }
    }
    double v = acc + (double)bias[co];
    rpn[(size_t)co * 16384 + y * 128 + x] = (float)(v > 0.0 ? v : 0.0);
}

// ==================== 1x1 heads, f64 accumulate ====================
// j<9: cls channel j; j>=9: box channel c=j-9 -> (a=c/4, comp=c%4)
__global__ __launch_bounds__(256)
void k_head64(const float* __restrict__ rpn, const float* __restrict__ clsw,
              const float* __restrict__ boxw, const float* __restrict__ clsb,
              const float* __restrict__ boxb, double* __restrict__ scoresD,
              double* __restrict__ deltasD) {
    int j = blockIdx.x;                              // 0..44
    int p = blockIdx.y * 256 + threadIdx.x;          // 0..16383
    const float* w = (j < 9) ? (clsw + j * 512) : (boxw + (j - 9) * 512);
    double acc = 0.0;
    for (int ci = 0; ci < 512; ++ci)
        acc = fma((double)w[ci], (double)rpn[(size_t)ci * 16384 + p], acc);
    if (j < 9) {
        double logit = acc + (double)clsb[j];
        scoresD[(size_t)p * 9 + j] = 1.0 / (1.0 + exp(-logit));
    } else {
        int c = j - 9;
        deltasD[((size_t)p * 9 + (c >> 2)) * 4 + (c & 3)] = acc + (double)boxb[c];
    }
}

// ==================== exact (score f64 desc, idx asc) global bitonic ====================
__global__ __launch_bounds__(256)
void k_fill2(const double* __restrict__ scoresD, double* __restrict__ sD, u64* __restrict__ idD) {
    int i = blockIdx.x * 256 + threadIdx.x;
    if (i < N_ANCH) { sD[i] = scoresD[i]; idD[i] = (u64)i; }
    else            { sD[i] = -1.0e300;   idD[i] = 0xFFFFFFFFFFFFFFFFull; }
}

__global__ __launch_bounds__(256)
void k_bstep2(double* __restrict__ sD, u64* __restrict__ idD, int k, int j) {
    int i = blockIdx.x * 256 + threadIdx.x;
    int l = i ^ j;
    if (l > i) {
        double as_ = sD[i], bs_ = sD[l];
        u64 ai = idD[i], bi = idD[l];
        bool agtb = (as_ > bs_) || (as_ == bs_ && ai < bi);   // a before b in desc order
        bool desc = ((i & k) == 0);
        if (desc ? !agtb : agtb) {
            sD[i] = bs_; sD[l] = as_;
            idD[i] = bi; idD[l] = ai;
        }
    }
}

// ==================== literal decode in f64 (anchors by formula) ====================
__global__ __launch_bounds__(256)
void k_decode2(const u64* __restrict__ idD, const double* __restrict__ deltasD,
               double* __restrict__ propsD, double* __restrict__ areaD,
               unsigned char* __restrict__ validb) {
    int r = blockIdx.x * 256 + threadIdx.x;
    if (r >= 2000) return;
    u32 idx = (u32)idD[r];
    int a = (int)(idx % 9u);
    u32 cell = idx / 9u;
    int yc = (int)(cell >> 7), xc = (int)(cell & 127u);
    const double ars[3] = {0.5, 1.0, 2.0};
    const double scl[3] = {128.0, 256.0, 512.0};
    double hr = sqrt(ars[a / 3]);          // anchor list is aspect-ratio-major
    double wr = 1.0 / hr;
    double wsv = wr * scl[a % 3];
    double hsv = hr * scl[a % 3];
    double bx1 = rint(-wsv / 2.0), bx2 = rint(wsv / 2.0);   // rint = half-even, like jnp.round
    double by1 = rint(-hsv / 2.0), by2 = rint(hsv / 2.0);
    double sx = 16.0 * (double)xc, sy = 16.0 * (double)yc;
    double ax1 = sx + bx1, ax2 = sx + bx2, ay1 = sy + by1, ay2 = sy + by2;
    double aw = ax2 - ax1, ah = ay2 - ay1;
    double acx = ax1 + 0.5 * aw, acy = ay1 + 0.5 * ah;
    const double BCLIP = 4.135166556742356;   // np.log(1000/16)
    double dx = deltasD[(size_t)idx * 4 + 0];
    double dy = deltasD[(size_t)idx * 4 + 1];
    double dw = fmin(deltasD[(size_t)idx * 4 + 2], BCLIP);
    double dh = fmin(deltasD[(size_t)idx * 4 + 3], BCLIP);
    double pcx = dx * aw + acx, pcy = dy * ah + acy;
    double pw = exp(dw) * aw,  ph = exp(dh) * ah;
    double x1 = pcx - 0.5 * pw, y1 = pcy - 0.5 * ph;
    double x2 = pcx + 0.5 * pw, y2 = pcy + 0.5 * ph;
    x1 = fmin(fmax(x1, 0.0), 2048.0);
    y1 = fmin(fmax(y1, 0.0), 2048.0);
    x2 = fmin(fmax(x2, 0.0), 2048.0);
    y2 = fmin(fmax(y2, 0.0), 2048.0);
    double wsz = x2 - x1, hsz = y2 - y1;
    propsD[(size_t)r * 4 + 0] = x1;
    propsD[(size_t)r * 4 + 1] = y1;
    propsD[(size_t)r * 4 + 2] = x2;
    propsD[(size_t)r * 4 + 3] = y2;
    areaD[r] = wsz * hsz;
    validb[r] = (wsz >= 16.0 && hsz >= 16.0) ? 1 : 0;
}

// ==================== literal gather NMS (fori_loop transcription) ====================
// keep[i] = valid[i] && !any(iou(i,j)>0.7 && keep[j] && j<i). IoU computed on the fly.
__global__ __launch_bounds__(64)
void k_nms2(const double* __restrict__ propsD, const double* __restrict__ areaD,
            const unsigned char* __restrict__ validb, unsigned char* __restrict__ keep) {
    __shared__ unsigned char K[2000];
    int lane = threadIdx.x;
    for (int i = lane; i < 2000; i += 64) K[i] = validb[i];
    __syncthreads();
    for (int i = 1; i < 2000; ++i) {
        if (K[i]) {
            double ix1 = propsD[(size_t)i * 4 + 0], iy1 = propsD[(size_t)i * 4 + 1];
            double ix2 = propsD[(size_t)i * 4 + 2], iy2 = propsD[(size_t)i * 4 + 3];
            double ia = areaD[i];
            bool sup = false;
            int nw = (i + 63) >> 6;
            for (int w = 0; w < nw; ++w) {
                int j = (w << 6) + lane;
                bool b = false;
                if (j < i && K[j]) {
                    double xx1 = fmax(ix1, propsD[(size_t)j * 4 + 0]);
                    double yy1 = fmax(iy1, propsD[(size_t)j * 4 + 1]);
                    double xx2 = fmin(ix2, propsD[(size_t)j * 4 + 2]);
                    double yy2 = fmin(iy2, propsD[(size_t)j * 4 + 3]);
                    double iw_ = fmax(xx2 - xx1, 0.0);
                    double ih_ = fmax(yy2 - yy1, 0.0);
                    double inter = iw_ * ih_;
                    double uni = ia + areaD[j] - inter;
                    b = (inter / fmax(uni, 1e-9)) > 0.7;
                }
                if (__ballot(b) != 0ull) { sup = true; break; }
            }
            if (sup) K[i] = 0;   // wave-uniform value
        }
        __syncthreads();
    }
    for (int i = lane; i < 2000; i += 64) keep[i] = K[i];
}

// ==================== literal top_k(final_scores, 1000) by repeated argmax ====================
__global__ __launch_bounds__(64)
void k_final2(const unsigned char* __restrict__ keep, const double* __restrict__ sD,
              const double* __restrict__ propsD, float* __restrict__ out) {
    __shared__ double FS[2048];
    int lane = threadIdx.x;
    for (int i = lane; i < 2048; i += 64)
        FS[i] = (i < 2000) ? (keep[i] ? sD[i] : -1.0) : -3.0;
    __syncthreads();
    for (int rank = 0; rank < 1000; ++rank) {
        double bs_ = -1.0e30; int bi = 1 << 20;
        for (int w = 0; w < 32; ++w) {
            int i = (w << 6) + lane;
            double s = FS[i];
            if (s > bs_ || (s == bs_ && i < bi)) { bs_ = s; bi = i; }
        }
        for (int off = 32; off > 0; off >>= 1) {   // wave argmax, tie -> lowest index
            double os = __shfl_xor(bs_, off, 64);
            int oi = __shfl_xor(bi, off, 64);
            if (os > bs_ || (os == bs_ && oi < bi)) { bs_ = os; bi = oi; }
        }
        if (lane < 4)
            out[rank * 4 + lane] = (bs_ > 0.0) ? (float)propsD[(size_t)bi * 4 + lane] : 0.0f;
        if (lane == 0) {
            out[4000 + rank] = (float)bs_;
            FS[bi] = -3.0;
        }
        __syncthreads();
    }
}

// ==================== launch ====================
extern "C" void kernel_launch(void* const* d_in, const int* in_sizes, int n_in,
                              void* d_out, int out_size, void* d_ws, size_t ws_size,
                              hipStream_t stream) {
    const float *feat = nullptr, *convw = nullptr, *convb = nullptr,
                *clsw = nullptr, *clsb = nullptr, *boxw = nullptr, *boxb = nullptr;
    for (int i = 0; i < n_in; ++i) {
        switch (in_sizes[i]) {
            case 8388608:  feat  = (const float*)d_in[i]; break;  // 512*128*128
            case 2359296:  convw = (const float*)d_in[i]; break;  // 512*512*9
            case 512:      convb = (const float*)d_in[i]; break;
            case 4608:     clsw  = (const float*)d_in[i]; break;  // 9*512
            case 9:        clsb  = (const float*)d_in[i]; break;
            case 18432:    boxw  = (const float*)d_in[i]; break;  // 36*512
            case 36:       boxb  = (const float*)d_in[i]; break;
            default: break;  // image (12582912) unused (only its shape matters)
        }
    }
    float* out = (float*)d_out;

    char* ws = (char*)d_ws;
    size_t off = 0;
    auto alloc = [&](size_t bytes) -> char* {
        char* p = ws + off;
        off += (bytes + 255) & ~(size_t)255;
        return p;
    };
    float*  rpn     = (float*)alloc((size_t)512 * 16384 * 4);    // 32 MB
    double* scoresD = (double*)alloc((size_t)N_ANCH * 8);        // 1.2 MB
    double* deltasD = (double*)alloc((size_t)N_ANCH * 4 * 8);    // 4.7 MB
    double* sD      = (double*)alloc((size_t)SORT_N * 8);        // 2 MB
    u64*    idD     = (u64*)alloc((size_t)SORT_N * 8);           // 2 MB
    double* propsD  = (double*)alloc((size_t)2000 * 4 * 8);
    double* areaD   = (double*)alloc((size_t)2000 * 8);
    unsigned char* validb = (unsigned char*)alloc(2048);
    unsigned char* keepb  = (unsigned char*)alloc(2048);
    (void)ws_size; (void)n_in; (void)out_size;

    k_conv64<<<dim3(128, 512), dim3(128), 0, stream>>>(feat, convw, convb, rpn);
    k_head64<<<dim3(45, 64), dim3(256), 0, stream>>>(rpn, clsw, boxw, clsb, boxb, scoresD, deltasD);
    k_fill2<<<dim3(SORT_N / 256), dim3(256), 0, stream>>>(scoresD, sD, idD);
    for (int k = 2; k <= SORT_N; k <<= 1)
        for (int j = k >> 1; j >= 1; j >>= 1)
            k_bstep2<<<dim3(SORT_N / 256), dim3(256), 0, stream>>>(sD, idD, k, j);
    k_decode2<<<dim3(8), dim3(256), 0, stream>>>(idD, deltasD, propsD, areaD, validb);
    k_nms2<<<dim3(1), dim3(64), 0, stream>>>(propsD, areaD, validb, keepb);
    k_final2<<<dim3(1), dim3(64), 0, stream>>>(keepb, sD, propsD, out);
}